// Round 5
// baseline (155.241 us; speedup 1.0000x reference)
//
#include <hip/hip_runtime.h>

typedef float v2f __attribute__((ext_vector_type(2)));

#define W_IMG   128
#define H_IMG   128
#define HW_IMG  16384
#define FX_C    128.0f
#define FY_C    128.0f
#define CX_C    64.0f
#define CY_C    64.0f
#define LOG2E_F 1.4426950408889634f

// ---------------------------------------------------------------------------
// Inline per-gaussian projection: returns {px, py, a2, op},
// a2 = -0.5/var * log2(e). ~60 VALU ops; qv/tv loads are uniform (cached).
// ---------------------------------------------------------------------------
__device__ __forceinline__ float4 proj_of(
    const float* __restrict__ pos, const float* __restrict__ opac,
    const float* __restrict__ scl, const float* __restrict__ qv,
    const float* __restrict__ tv, int i)
{
    float qw = qv[0], qx = qv[1], qy = qv[2], qz = qv[3];
    float qn = sqrtf(qw*qw + qx*qx + qy*qy + qz*qz);
    qw /= qn; qx /= qn; qy /= qn; qz /= qn;

    float R00 = 1.f - 2.f*(qy*qy + qz*qz), R01 = 2.f*(qx*qy - qz*qw), R02 = 2.f*(qx*qz + qy*qw);
    float R10 = 2.f*(qx*qy + qz*qw), R11 = 1.f - 2.f*(qx*qx + qz*qz), R12 = 2.f*(qy*qz - qx*qw);
    float R20 = 2.f*(qx*qz - qy*qw), R21 = 2.f*(qy*qz + qx*qw), R22 = 1.f - 2.f*(qx*qx + qy*qy);

    float x = pos[3*i + 0];
    float y = pos[3*i + 1];
    float z = pos[3*i + 2];

    float cx = R00*x + R01*y + R02*z + tv[0];
    float cy = R10*x + R11*y + R12*z + tv[1];
    float cz = R20*x + R21*y + R22*z + tv[2];

    float px = cx / cz * FX_C + CX_C;
    float py = cy / cz * FY_C + CY_C;

    float s   = scl[i];
    float a2  = (-0.5f / (s * s)) * LOG2E_F;

    float4 r; r.x = px; r.y = py; r.z = a2; r.w = opac[i];
    return r;
}

// ---------------------------------------------------------------------------
// Kernel 1 (fused prep+factor): N*128 threads.
//   U[g*128 + x] = op_g * 2^(a2_g (x-px_g)^2)   (write coalesced)
//   Vt[y*N + g]  =        2^(a2_g (y-py_g)^2)   (write coalesced)
//   colors4[g]   = {cr,cg,cb,0}                 (aligned for s_load_dwordx4)
// proj recomputed inline (~3 us total) to save a dispatch (~17 us).
// ---------------------------------------------------------------------------
__global__ __launch_bounds__(256) void factor2_kernel(
    const float* __restrict__ pos, const float* __restrict__ col,
    const float* __restrict__ opac, const float* __restrict__ scl,
    const float* __restrict__ qv, const float* __restrict__ tv,
    float* __restrict__ U, float* __restrict__ Vt, float4* __restrict__ colors4,
    int N, int yshift)
{
    int idx = blockIdx.x * 256 + threadIdx.x;

    // U element: gaussian idx>>7 (wave-uniform-ish), x = idx&127
    float4 pU = proj_of(pos, opac, scl, qv, tv, idx >> 7);
    float dx = (float)(idx & 127) - pU.x;
    U[idx] = pU.w * __builtin_amdgcn_exp2f(pU.z * dx * dx);

    // Vt element: y = idx>>yshift, g = low bits (coalesced)
    int yv = (yshift >= 0) ? (idx >> yshift) : (idx / N);
    int g2 = idx - yv * N;
    float4 pV = proj_of(pos, opac, scl, qv, tv, g2);
    float dy = (float)yv - pV.y;
    Vt[idx] = __builtin_amdgcn_exp2f(pV.z * dy * dy);

    if (idx < N) {
        float4 c; c.x = col[3*idx+0]; c.y = col[3*idx+1]; c.z = col[3*idx+2]; c.w = 0.f;
        colors4[idx] = c;
    }
}

// ---------------------------------------------------------------------------
// Kernel 2 (hot): rank-1 accumulation. Block = 4 y-rows x 128 x (2 px/thread,
// packed fp32). grid = (32, S). Per j: 1 coalesced dwordx2 (U) + uniform
// s_loads (Vt row, colors4) + 6 packed VALU for 128 pairs.
// launch_bounds(256,8): cap VGPR at 64 so 8 blocks/CU stay resident.
// ---------------------------------------------------------------------------
__global__ __launch_bounds__(256, 8) void gemm_kernel(
    const float* __restrict__ U, const float* __restrict__ Vt,
    const float4* __restrict__ colors4, float4* __restrict__ part,
    int segLen, int N)
{
    int tid = threadIdx.x;
    int x2  = tid & 63;                    // x-pair: pixels 2*x2, 2*x2+1
    int ys  = __builtin_amdgcn_readfirstlane(blockIdx.x * 4 + (tid >> 6));

    const float* __restrict__ Vrow = Vt + (size_t)ys * N;
    int g0 = blockIdx.y * segLen;
    const v2f* __restrict__ up = (const v2f*)(U + (size_t)g0 * 128) + x2;

    v2f nr = 0.f, ng = 0.f, nb = 0.f, den = 0.f;

    #pragma unroll 16
    for (int j = 0; j < segLen; ++j) {
        v2f   u = up[(size_t)j * 64];      // coalesced 512 B/wave
        float v = Vrow[g0 + j];            // uniform -> s_load
        float4 c = colors4[g0 + j];        // uniform -> s_load_dwordx4
        v2f w = u * v;
        nr  += w * c.x;
        ng  += w * c.y;
        nb  += w * c.z;
        den += w;
    }

    size_t base = (size_t)blockIdx.y * HW_IMG + ys * 128 + 2 * x2;
    float4 o0; o0.x = nr.x; o0.y = ng.x; o0.z = nb.x; o0.w = den.x;
    float4 o1; o1.x = nr.y; o1.y = ng.y; o1.z = nb.y; o1.w = den.y;
    part[base]     = o0;
    part[base + 1] = o1;
}

// ---------------------------------------------------------------------------
// Fallback hot kernel (tiny-workspace path only): direct 2-D evaluation.
// ---------------------------------------------------------------------------
__global__ __launch_bounds__(256) void render_fb(
    const float* __restrict__ pos, const float* __restrict__ col,
    const float* __restrict__ opac, const float* __restrict__ scl,
    const float* __restrict__ qv, const float* __restrict__ tv,
    float4* __restrict__ part, int segLen)
{
    int p = blockIdx.x * 256 + threadIdx.x;
    float X = (float)(p & (W_IMG - 1));
    float Y = (float)(p >> 7);

    int g0 = blockIdx.y * segLen;
    float nr = 0.f, ng = 0.f, nb = 0.f, den = 0.f;
    for (int j = 0; j < segLen; ++j) {
        int g = g0 + j;
        float4 pg = proj_of(pos, opac, scl, qv, tv, g);
        float dx = X - pg.x;
        float dy = Y - pg.y;
        float d2 = fmaf(dx, dx, dy * dy);
        float e  = pg.w * __builtin_amdgcn_exp2f(pg.z * d2);
        nr  = fmaf(e, col[3*g+0], nr);
        ng  = fmaf(e, col[3*g+1], ng);
        nb  = fmaf(e, col[3*g+2], nb);
        den += e;
    }
    float4 o; o.x = nr; o.y = ng; o.z = nb; o.w = den;
    part[(size_t)blockIdx.y * HW_IMG + p] = o;
}

// ---------------------------------------------------------------------------
// Kernel 3: reduce segments, add n_chunks*EPS, divide, tiled/transposed fp32
// output: out[t, c, s/tile, s%tile], p = t*step + s, step = tile^2.
// ---------------------------------------------------------------------------
__global__ __launch_bounds__(256) void finalize_kernel(
    const float4* __restrict__ part, float* __restrict__ out,
    const int* __restrict__ chunk_gauss_p, const int* __restrict__ tile_hw_p,
    int N, int nseg)
{
    int p = blockIdx.x * 256 + threadIdx.x;

    float nr = 0.f, ng = 0.f, nb = 0.f, den = 0.f;
    #pragma unroll 4
    for (int s = 0; s < nseg; ++s) {
        float4 v = part[(size_t)s * HW_IMG + p];
        nr += v.x; ng += v.y; nb += v.z; den += v.w;
    }

    int cg = chunk_gauss_p[0];
    int n_chunks = (cg > 0) ? (N / cg) : 0;
    den += (float)n_chunks * 1e-8f;   // EPS added once per scan chunk

    int th   = tile_hw_p[0];
    int step = th * th;
    if (step <= 0 || step > HW_IMG) { th = 64; step = th * th; }
    int t  = p / step;
    int s2 = p - t * step;
    size_t base = (size_t)t * 3 * step + s2;

    out[base]            = nr / den;
    out[base + step]     = ng / den;
    out[base + 2 * step] = nb / den;
}

extern "C" void kernel_launch(void* const* d_in, const int* in_sizes, int n_in,
                              void* d_out, int out_size, void* d_ws, size_t ws_size,
                              hipStream_t stream)
{
    const float* pos  = (const float*)d_in[0];
    const float* col  = (const float*)d_in[1];
    const float* opac = (const float*)d_in[2];
    const float* scl  = (const float*)d_in[3];
    const float* qv   = (const float*)d_in[4];
    const float* tv   = (const float*)d_in[5];
    const int* tile_hw_p     = (const int*)d_in[6];
    const int* chunk_gauss_p = (const int*)d_in[7];

    int N = in_sizes[2];                 // one opacity per gaussian

    int yshift = -1;
    if ((N & (N - 1)) == 0) { yshift = 0; while ((1 << yshift) < N) ++yshift; }

    // Workspace layout: [colors4 N f4][U N*128 f][Vt 128*N f][part S*HW f4]
    size_t colB    = (size_t)N * 16;
    size_t factorB = (size_t)N * 128 * 4 * 2;

    int S = 0;
    for (int cand = 64; cand >= 8; cand >>= 1) {
        if (N % cand == 0 &&
            colB + factorB + (size_t)cand * HW_IMG * 16 <= ws_size) { S = cand; break; }
    }

    if (S > 0) {
        float4* colors4 = (float4*)d_ws;
        float*  U       = (float*)((char*)d_ws + colB);
        float*  Vt      = U + (size_t)N * 128;
        float4* part    = (float4*)((char*)d_ws + colB + factorB);

        factor2_kernel<<<(N * 128) / 256, 256, 0, stream>>>(
            pos, col, opac, scl, qv, tv, U, Vt, colors4, N, yshift);

        dim3 grid(H_IMG / 4, S);
        gemm_kernel<<<grid, 256, 0, stream>>>(U, Vt, colors4, part, N / S, N);

        finalize_kernel<<<HW_IMG / 256, 256, 0, stream>>>(
            part, (float*)d_out, chunk_gauss_p, tile_hw_p, N, S);
    } else {
        // Tiny-workspace fallback: direct evaluation, no factor tables.
        int nseg = 16;
        while (nseg > 1 &&
               ((size_t)nseg * HW_IMG * 16 > ws_size || (N % nseg) != 0))
            nseg >>= 1;
        float4* part = (float4*)d_ws;

        dim3 grid(HW_IMG / 256, nseg);
        render_fb<<<grid, 256, 0, stream>>>(pos, col, opac, scl, qv, tv, part, N / nseg);

        finalize_kernel<<<HW_IMG / 256, 256, 0, stream>>>(
            part, (float*)d_out, chunk_gauss_p, tile_hw_p, N, nseg);
    }
}

// Round 6
// 130.960 us; speedup vs baseline: 1.1854x; 1.1854x over previous
//
#include <hip/hip_runtime.h>

typedef float v2f __attribute__((ext_vector_type(2)));

#define W_IMG   128
#define H_IMG   128
#define HW_IMG  16384
#define FX_C    128.0f
#define FY_C    128.0f
#define CX_C    64.0f
#define CY_C    64.0f
#define LOG2E_F 1.4426950408889634f

// ---------------------------------------------------------------------------
// Inline per-gaussian projection: {px, py, a2, op}, a2 = -0.5/var*log2(e).
// ---------------------------------------------------------------------------
__device__ __forceinline__ float4 proj_of(
    const float* __restrict__ pos, const float* __restrict__ opac,
    const float* __restrict__ scl, const float* __restrict__ qv,
    const float* __restrict__ tv, int i)
{
    float qw = qv[0], qx = qv[1], qy = qv[2], qz = qv[3];
    float qn = sqrtf(qw*qw + qx*qx + qy*qy + qz*qz);
    qw /= qn; qx /= qn; qy /= qn; qz /= qn;

    float R00 = 1.f - 2.f*(qy*qy + qz*qz), R01 = 2.f*(qx*qy - qz*qw), R02 = 2.f*(qx*qz + qy*qw);
    float R10 = 2.f*(qx*qy + qz*qw), R11 = 1.f - 2.f*(qx*qx + qz*qz), R12 = 2.f*(qy*qz - qx*qw);
    float R20 = 2.f*(qx*qz - qy*qw), R21 = 2.f*(qy*qz + qx*qw), R22 = 1.f - 2.f*(qx*qx + qy*qy);

    float x = pos[3*i + 0];
    float y = pos[3*i + 1];
    float z = pos[3*i + 2];

    float cx = R00*x + R01*y + R02*z + tv[0];
    float cy = R10*x + R11*y + R12*z + tv[1];
    float cz = R20*x + R21*y + R22*z + tv[2];

    float px = cx / cz * FX_C + CX_C;
    float py = cy / cz * FY_C + CY_C;

    float s   = scl[i];
    float a2  = (-0.5f / (s * s)) * LOG2E_F;

    float4 r; r.x = px; r.y = py; r.z = a2; r.w = opac[i];
    return r;
}

// ---------------------------------------------------------------------------
// Kernel 1 (fused prep+factor): N*128 threads; g = idx>>7, coord = idx&127.
//   U[g*128 + x] = op_g * 2^(a2 (x-px)^2)    (coalesced)
//   Vt[g*128 + y] =       2^(a2 (y-py)^2)    (coalesced, y-minor layout!)
//   colors4[g]   = {cr,cg,cb,0}
// One proj per thread (g is uniform across the 128-thread row).
// ---------------------------------------------------------------------------
__global__ __launch_bounds__(256) void factor2_kernel(
    const float* __restrict__ pos, const float* __restrict__ col,
    const float* __restrict__ opac, const float* __restrict__ scl,
    const float* __restrict__ qv, const float* __restrict__ tv,
    float* __restrict__ U, float* __restrict__ Vt, float4* __restrict__ colors4,
    int N)
{
    int idx = blockIdx.x * 256 + threadIdx.x;
    int g   = idx >> 7;
    float t = (float)(idx & 127);

    float4 p = proj_of(pos, opac, scl, qv, tv, g);
    float dx = t - p.x;
    float dy = t - p.y;
    U[idx]  = p.w * __builtin_amdgcn_exp2f(p.z * dx * dx);
    Vt[idx] =       __builtin_amdgcn_exp2f(p.z * dy * dy);

    if (idx < N) {
        float4 c; c.x = col[3*idx+0]; c.y = col[3*idx+1]; c.z = col[3*idx+2]; c.w = 0.f;
        colors4[idx] = c;
    }
}

// ---------------------------------------------------------------------------
// Kernel 2 (hot): register-tiled rank-1 accumulation.
// Thread tile = 2x * 4y = 8 px. Wave = 64 x-threads (full 128-px row),
// 4 waves/block stacked in y -> block = 128x * 16y. grid = (8, S).
// Per gaussian per wave: 1 coalesced dwordx2 (u, reused 4x) +
// uniform s_load_dwordx4 (v for 4 y) + s_load_dwordx4 (color) + 20 pk ops.
// No occupancy cap: compiler needs VGPRs for unroll-8 load pipelining.
// ---------------------------------------------------------------------------
__global__ __launch_bounds__(256) void gemm_kernel(
    const float* __restrict__ U, const float* __restrict__ Vt,
    const float4* __restrict__ colors4, float4* __restrict__ part,
    int segLen)
{
    int tid = threadIdx.x;
    int xt  = tid & 63;                                       // x-pair index
    int y0  = __builtin_amdgcn_readfirstlane(blockIdx.x * 16 + (tid >> 6) * 4);

    int g0 = blockIdx.y * segLen;

    const v2f*    __restrict__ up = (const v2f*)(U + (size_t)g0 * 128) + xt;
    const float4* __restrict__ vp = (const float4*)(Vt + (size_t)g0 * 128 + y0);
    const float4* __restrict__ cp = colors4 + g0;

    v2f ar0 = 0.f, ag0 = 0.f, ab0 = 0.f, ad0 = 0.f;
    v2f ar1 = 0.f, ag1 = 0.f, ab1 = 0.f, ad1 = 0.f;
    v2f ar2 = 0.f, ag2 = 0.f, ab2 = 0.f, ad2 = 0.f;
    v2f ar3 = 0.f, ag3 = 0.f, ab3 = 0.f, ad3 = 0.f;

    #pragma unroll 8
    for (int j = 0; j < segLen; ++j) {
        v2f    u  = up[(size_t)j * 64];    // 512 B/wave, coalesced
        float4 v4 = vp[(size_t)j * 32];    // wave-uniform -> s_load_dwordx4
        float4 c  = cp[j];                 // wave-uniform -> s_load_dwordx4

        v2f w0 = u * v4.x;
        v2f w1 = u * v4.y;
        v2f w2 = u * v4.z;
        v2f w3 = u * v4.w;

        ar0 += w0 * c.x; ag0 += w0 * c.y; ab0 += w0 * c.z; ad0 += w0;
        ar1 += w1 * c.x; ag1 += w1 * c.y; ab1 += w1 * c.z; ad1 += w1;
        ar2 += w2 * c.x; ag2 += w2 * c.y; ab2 += w2 * c.z; ad2 += w2;
        ar3 += w3 * c.x; ag3 += w3 * c.y; ab3 += w3 * c.z; ad3 += w3;
    }

    size_t segBase = (size_t)blockIdx.y * HW_IMG + 2 * xt;
    {
        size_t b = segBase + (size_t)(y0 + 0) * 128;
        float4 o0; o0.x = ar0.x; o0.y = ag0.x; o0.z = ab0.x; o0.w = ad0.x;
        float4 o1; o1.x = ar0.y; o1.y = ag0.y; o1.z = ab0.y; o1.w = ad0.y;
        part[b] = o0; part[b + 1] = o1;
    }
    {
        size_t b = segBase + (size_t)(y0 + 1) * 128;
        float4 o0; o0.x = ar1.x; o0.y = ag1.x; o0.z = ab1.x; o0.w = ad1.x;
        float4 o1; o1.x = ar1.y; o1.y = ag1.y; o1.z = ab1.y; o1.w = ad1.y;
        part[b] = o0; part[b + 1] = o1;
    }
    {
        size_t b = segBase + (size_t)(y0 + 2) * 128;
        float4 o0; o0.x = ar2.x; o0.y = ag2.x; o0.z = ab2.x; o0.w = ad2.x;
        float4 o1; o1.x = ar2.y; o1.y = ag2.y; o1.z = ab2.y; o1.w = ad2.y;
        part[b] = o0; part[b + 1] = o1;
    }
    {
        size_t b = segBase + (size_t)(y0 + 3) * 128;
        float4 o0; o0.x = ar3.x; o0.y = ag3.x; o0.z = ab3.x; o0.w = ad3.x;
        float4 o1; o1.x = ar3.y; o1.y = ag3.y; o1.z = ab3.y; o1.w = ad3.y;
        part[b] = o0; part[b + 1] = o1;
    }
}

// ---------------------------------------------------------------------------
// Fallback hot kernel (tiny-workspace path only): direct 2-D evaluation.
// ---------------------------------------------------------------------------
__global__ __launch_bounds__(256) void render_fb(
    const float* __restrict__ pos, const float* __restrict__ col,
    const float* __restrict__ opac, const float* __restrict__ scl,
    const float* __restrict__ qv, const float* __restrict__ tv,
    float4* __restrict__ part, int segLen)
{
    int p = blockIdx.x * 256 + threadIdx.x;
    float X = (float)(p & (W_IMG - 1));
    float Y = (float)(p >> 7);

    int g0 = blockIdx.y * segLen;
    float nr = 0.f, ng = 0.f, nb = 0.f, den = 0.f;
    for (int j = 0; j < segLen; ++j) {
        int g = g0 + j;
        float4 pg = proj_of(pos, opac, scl, qv, tv, g);
        float dx = X - pg.x;
        float dy = Y - pg.y;
        float d2 = fmaf(dx, dx, dy * dy);
        float e  = pg.w * __builtin_amdgcn_exp2f(pg.z * d2);
        nr  = fmaf(e, col[3*g+0], nr);
        ng  = fmaf(e, col[3*g+1], ng);
        nb  = fmaf(e, col[3*g+2], nb);
        den += e;
    }
    float4 o; o.x = nr; o.y = ng; o.z = nb; o.w = den;
    part[(size_t)blockIdx.y * HW_IMG + p] = o;
}

// ---------------------------------------------------------------------------
// Kernel 3: reduce segments, add n_chunks*EPS, divide, tiled/transposed fp32
// output: out[t, c, s/tile, s%tile], p = t*step + s, step = tile^2.
// ---------------------------------------------------------------------------
__global__ __launch_bounds__(256) void finalize_kernel(
    const float4* __restrict__ part, float* __restrict__ out,
    const int* __restrict__ chunk_gauss_p, const int* __restrict__ tile_hw_p,
    int N, int nseg)
{
    int p = blockIdx.x * 256 + threadIdx.x;

    float nr = 0.f, ng = 0.f, nb = 0.f, den = 0.f;
    #pragma unroll 8
    for (int s = 0; s < nseg; ++s) {
        float4 v = part[(size_t)s * HW_IMG + p];
        nr += v.x; ng += v.y; nb += v.z; den += v.w;
    }

    int cg = chunk_gauss_p[0];
    int n_chunks = (cg > 0) ? (N / cg) : 0;
    den += (float)n_chunks * 1e-8f;   // EPS added once per scan chunk

    int th   = tile_hw_p[0];
    int step = th * th;
    if (step <= 0 || step > HW_IMG) { th = 64; step = th * th; }
    int t  = p / step;
    int s2 = p - t * step;
    size_t base = (size_t)t * 3 * step + s2;

    out[base]            = nr / den;
    out[base + step]     = ng / den;
    out[base + 2 * step] = nb / den;
}

extern "C" void kernel_launch(void* const* d_in, const int* in_sizes, int n_in,
                              void* d_out, int out_size, void* d_ws, size_t ws_size,
                              hipStream_t stream)
{
    const float* pos  = (const float*)d_in[0];
    const float* col  = (const float*)d_in[1];
    const float* opac = (const float*)d_in[2];
    const float* scl  = (const float*)d_in[3];
    const float* qv   = (const float*)d_in[4];
    const float* tv   = (const float*)d_in[5];
    const int* tile_hw_p     = (const int*)d_in[6];
    const int* chunk_gauss_p = (const int*)d_in[7];

    int N = in_sizes[2];                 // one opacity per gaussian

    // Workspace layout: [colors4 N f4][U N*128 f][Vt N*128 f][part S*HW f4]
    size_t colB    = (size_t)N * 16;
    size_t factorB = (size_t)N * 128 * 4 * 2;

    int S = 0;
    for (int cand = 64; cand >= 8; cand >>= 1) {
        if (N % cand == 0 &&
            colB + factorB + (size_t)cand * HW_IMG * 16 <= ws_size) { S = cand; break; }
    }

    if (S > 0) {
        float4* colors4 = (float4*)d_ws;
        float*  U       = (float*)((char*)d_ws + colB);
        float*  Vt      = U + (size_t)N * 128;
        float4* part    = (float4*)((char*)d_ws + colB + factorB);

        factor2_kernel<<<(N * 128) / 256, 256, 0, stream>>>(
            pos, col, opac, scl, qv, tv, U, Vt, colors4, N);

        dim3 grid(H_IMG / 16, S);
        gemm_kernel<<<grid, 256, 0, stream>>>(U, Vt, colors4, part, N / S);

        finalize_kernel<<<HW_IMG / 256, 256, 0, stream>>>(
            part, (float*)d_out, chunk_gauss_p, tile_hw_p, N, S);
    } else {
        // Tiny-workspace fallback: direct evaluation, no factor tables.
        int nseg = 16;
        while (nseg > 1 &&
               ((size_t)nseg * HW_IMG * 16 > ws_size || (N % nseg) != 0))
            nseg >>= 1;
        float4* part = (float4*)d_ws;

        dim3 grid(HW_IMG / 256, nseg);
        render_fb<<<grid, 256, 0, stream>>>(pos, col, opac, scl, qv, tv, part, N / nseg);

        finalize_kernel<<<HW_IMG / 256, 256, 0, stream>>>(
            part, (float*)d_out, chunk_gauss_p, tile_hw_p, N, nseg);
    }
}

// Round 7
// 118.412 us; speedup vs baseline: 1.3110x; 1.1060x over previous
//
#include <hip/hip_runtime.h>

typedef float v2f __attribute__((ext_vector_type(2)));

#define W_IMG   128
#define H_IMG   128
#define HW_IMG  16384
#define FX_C    128.0f
#define FY_C    128.0f
#define CX_C    64.0f
#define CY_C    64.0f
#define LOG2E_F 1.4426950408889634f
#define CHUNK   64

// ---------------------------------------------------------------------------
// Inline per-gaussian projection: {px, py, a2, op}, a2 = -0.5/var*log2(e).
// ---------------------------------------------------------------------------
__device__ __forceinline__ float4 proj_of(
    const float* __restrict__ pos, const float* __restrict__ opac,
    const float* __restrict__ scl, const float* __restrict__ qv,
    const float* __restrict__ tv, int i)
{
    float qw = qv[0], qx = qv[1], qy = qv[2], qz = qv[3];
    float qn = sqrtf(qw*qw + qx*qx + qy*qy + qz*qz);
    qw /= qn; qx /= qn; qy /= qn; qz /= qn;

    float R00 = 1.f - 2.f*(qy*qy + qz*qz), R01 = 2.f*(qx*qy - qz*qw), R02 = 2.f*(qx*qz + qy*qw);
    float R10 = 2.f*(qx*qy + qz*qw), R11 = 1.f - 2.f*(qx*qx + qz*qz), R12 = 2.f*(qy*qz - qx*qw);
    float R20 = 2.f*(qx*qz - qy*qw), R21 = 2.f*(qy*qz + qx*qw), R22 = 1.f - 2.f*(qx*qx + qy*qy);

    float x = pos[3*i + 0];
    float y = pos[3*i + 1];
    float z = pos[3*i + 2];

    float cx = R00*x + R01*y + R02*z + tv[0];
    float cy = R10*x + R11*y + R12*z + tv[1];
    float cz = R20*x + R21*y + R22*z + tv[2];

    float px = cx / cz * FX_C + CX_C;
    float py = cy / cz * FY_C + CY_C;

    float s   = scl[i];
    float a2  = (-0.5f / (s * s)) * LOG2E_F;

    float4 r; r.x = px; r.y = py; r.z = a2; r.w = opac[i];
    return r;
}

// ---------------------------------------------------------------------------
// Fused hot kernel: factor tables computed on the fly into LDS, then
// register-tiled rank-1 accumulation out of LDS.
// Block = 128x * 16y px, thread tile 2x*4y, 4 waves. grid = (8, S).
// Per chunk of 64 gaussians: stage proj (64 thr) -> U[64][128] (32 KB) and
// V[64][16] (4 KB) in LDS -> inner loop: ds_read_b64 (2-way alias, free) +
// broadcast b128 + uniform scalar color loads + 20 packed VALU per 8 px.
// LDS 37 KB -> 4 blocks/CU; launch_bounds(256,4) caps VGPR at 128.
// ---------------------------------------------------------------------------
__global__ __launch_bounds__(256, 4) void gemm_fused(
    const float* __restrict__ pos, const float* __restrict__ col,
    const float* __restrict__ opac, const float* __restrict__ scl,
    const float* __restrict__ qv, const float* __restrict__ tv,
    float4* __restrict__ part, int segLen)
{
    __shared__ __align__(16) float  U_lds[CHUNK * 128];
    __shared__ __align__(16) float  V_lds[CHUNK * 16];
    __shared__ __align__(16) float4 P_lds[CHUNK];

    int tid = threadIdx.x;
    int xt  = tid & 63;                   // x-pair index within the 128-px row
    int wy  = (tid >> 6) * 4;             // wave's y offset within block tile
    int yb  = blockIdx.x * 16;            // block's y base
    int g0  = blockIdx.y * segLen;

    v2f ar0 = 0.f, ag0 = 0.f, ab0 = 0.f, ad0 = 0.f;
    v2f ar1 = 0.f, ag1 = 0.f, ab1 = 0.f, ad1 = 0.f;
    v2f ar2 = 0.f, ag2 = 0.f, ab2 = 0.f, ad2 = 0.f;
    v2f ar3 = 0.f, ag3 = 0.f, ab3 = 0.f, ad3 = 0.f;

    for (int c0 = 0; c0 < segLen; c0 += CHUNK) {
        int cc = (segLen - c0 < CHUNK) ? (segLen - c0) : CHUNK;

        __syncthreads();                           // LDS reuse guard
        if (tid < cc)
            P_lds[tid] = proj_of(pos, opac, scl, qv, tv, g0 + c0 + tid);
        __syncthreads();

        // Stage U: e = g*128 + x, lanes consecutive -> conflict-free writes;
        // P_lds[e>>7] is wave-uniform -> broadcast read.
        for (int e = tid; e < cc * 128; e += 256) {
            float4 p = P_lds[e >> 7];
            float dx = (float)(e & 127) - p.x;
            U_lds[e] = p.w * __builtin_amdgcn_exp2f(p.z * dx * dx);
        }
        // Stage V: e = g*16 + y (block-local y).
        for (int e = tid; e < cc * 16; e += 256) {
            float4 p = P_lds[e >> 4];
            float dy = (float)(yb + (e & 15)) - p.y;
            V_lds[e] = __builtin_amdgcn_exp2f(p.z * dy * dy);
        }
        __syncthreads();

        const float* __restrict__ colp = col + 3 * (g0 + c0);  // uniform base

        #pragma unroll 8
        for (int j = 0; j < cc; ++j) {
            v2f    u  = *(const v2f*)(U_lds + j * 128 + 2 * xt);   // ds_read_b64
            float4 v4 = *(const float4*)(V_lds + j * 16 + wy);     // broadcast b128
            float  cr = colp[3*j + 0];                             // uniform -> s_load
            float  cg = colp[3*j + 1];
            float  cb = colp[3*j + 2];

            v2f w0 = u * v4.x;
            v2f w1 = u * v4.y;
            v2f w2 = u * v4.z;
            v2f w3 = u * v4.w;

            ar0 += w0 * cr; ag0 += w0 * cg; ab0 += w0 * cb; ad0 += w0;
            ar1 += w1 * cr; ag1 += w1 * cg; ab1 += w1 * cb; ad1 += w1;
            ar2 += w2 * cr; ag2 += w2 * cg; ab2 += w2 * cb; ad2 += w2;
            ar3 += w3 * cr; ag3 += w3 * cg; ab3 += w3 * cb; ad3 += w3;
        }
    }

    size_t segBase = (size_t)blockIdx.y * HW_IMG + 2 * xt;
    {
        size_t b = segBase + (size_t)(yb + wy + 0) * 128;
        float4 o0; o0.x = ar0.x; o0.y = ag0.x; o0.z = ab0.x; o0.w = ad0.x;
        float4 o1; o1.x = ar0.y; o1.y = ag0.y; o1.z = ab0.y; o1.w = ad0.y;
        part[b] = o0; part[b + 1] = o1;
    }
    {
        size_t b = segBase + (size_t)(yb + wy + 1) * 128;
        float4 o0; o0.x = ar1.x; o0.y = ag1.x; o0.z = ab1.x; o0.w = ad1.x;
        float4 o1; o1.x = ar1.y; o1.y = ag1.y; o1.z = ab1.y; o1.w = ad1.y;
        part[b] = o0; part[b + 1] = o1;
    }
    {
        size_t b = segBase + (size_t)(yb + wy + 2) * 128;
        float4 o0; o0.x = ar2.x; o0.y = ag2.x; o0.z = ab2.x; o0.w = ad2.x;
        float4 o1; o1.x = ar2.y; o1.y = ag2.y; o1.z = ab2.y; o1.w = ad2.y;
        part[b] = o0; part[b + 1] = o1;
    }
    {
        size_t b = segBase + (size_t)(yb + wy + 3) * 128;
        float4 o0; o0.x = ar3.x; o0.y = ag3.x; o0.z = ab3.x; o0.w = ad3.x;
        float4 o1; o1.x = ar3.y; o1.y = ag3.y; o1.z = ab3.y; o1.w = ad3.y;
        part[b] = o0; part[b + 1] = o1;
    }
}

// ---------------------------------------------------------------------------
// Fallback hot kernel (tiny-workspace path only): direct 2-D evaluation.
// ---------------------------------------------------------------------------
__global__ __launch_bounds__(256) void render_fb(
    const float* __restrict__ pos, const float* __restrict__ col,
    const float* __restrict__ opac, const float* __restrict__ scl,
    const float* __restrict__ qv, const float* __restrict__ tv,
    float4* __restrict__ part, int segLen)
{
    int p = blockIdx.x * 256 + threadIdx.x;
    float X = (float)(p & (W_IMG - 1));
    float Y = (float)(p >> 7);

    int g0 = blockIdx.y * segLen;
    float nr = 0.f, ng = 0.f, nb = 0.f, den = 0.f;
    for (int j = 0; j < segLen; ++j) {
        int g = g0 + j;
        float4 pg = proj_of(pos, opac, scl, qv, tv, g);
        float dx = X - pg.x;
        float dy = Y - pg.y;
        float d2 = fmaf(dx, dx, dy * dy);
        float e  = pg.w * __builtin_amdgcn_exp2f(pg.z * d2);
        nr  = fmaf(e, col[3*g+0], nr);
        ng  = fmaf(e, col[3*g+1], ng);
        nb  = fmaf(e, col[3*g+2], nb);
        den += e;
    }
    float4 o; o.x = nr; o.y = ng; o.z = nb; o.w = den;
    part[(size_t)blockIdx.y * HW_IMG + p] = o;
}

// ---------------------------------------------------------------------------
// Finalize: reduce segments, add n_chunks*EPS, divide, tiled/transposed fp32
// output: out[t, c, s/tile, s%tile], p = t*step + s, step = tile^2.
// ---------------------------------------------------------------------------
__global__ __launch_bounds__(256) void finalize_kernel(
    const float4* __restrict__ part, float* __restrict__ out,
    const int* __restrict__ chunk_gauss_p, const int* __restrict__ tile_hw_p,
    int N, int nseg)
{
    int p = blockIdx.x * 256 + threadIdx.x;

    float nr = 0.f, ng = 0.f, nb = 0.f, den = 0.f;
    #pragma unroll 8
    for (int s = 0; s < nseg; ++s) {
        float4 v = part[(size_t)s * HW_IMG + p];
        nr += v.x; ng += v.y; nb += v.z; den += v.w;
    }

    int cg = chunk_gauss_p[0];
    int n_chunks = (cg > 0) ? (N / cg) : 0;
    den += (float)n_chunks * 1e-8f;   // EPS added once per scan chunk

    int th   = tile_hw_p[0];
    int step = th * th;
    if (step <= 0 || step > HW_IMG) { th = 64; step = th * th; }
    int t  = p / step;
    int s2 = p - t * step;
    size_t base = (size_t)t * 3 * step + s2;

    out[base]            = nr / den;
    out[base + step]     = ng / den;
    out[base + 2 * step] = nb / den;
}

extern "C" void kernel_launch(void* const* d_in, const int* in_sizes, int n_in,
                              void* d_out, int out_size, void* d_ws, size_t ws_size,
                              hipStream_t stream)
{
    const float* pos  = (const float*)d_in[0];
    const float* col  = (const float*)d_in[1];
    const float* opac = (const float*)d_in[2];
    const float* scl  = (const float*)d_in[3];
    const float* qv   = (const float*)d_in[4];
    const float* tv   = (const float*)d_in[5];
    const int* tile_hw_p     = (const int*)d_in[6];
    const int* chunk_gauss_p = (const int*)d_in[7];

    int N = in_sizes[2];                 // one opacity per gaussian

    // Workspace: only part[S * HW] float4 (factors live in LDS now).
    int S = 0;
    for (int cand = 128; cand >= 8; cand >>= 1) {
        if (N % cand == 0 &&
            (size_t)cand * HW_IMG * 16 <= ws_size) { S = cand; break; }
    }

    float4* part = (float4*)d_ws;

    if (S > 0) {
        dim3 grid(H_IMG / 16, S);
        gemm_fused<<<grid, 256, 0, stream>>>(
            pos, col, opac, scl, qv, tv, part, N / S);

        finalize_kernel<<<HW_IMG / 256, 256, 0, stream>>>(
            part, (float*)d_out, chunk_gauss_p, tile_hw_p, N, S);
    } else {
        int nseg = 16;
        while (nseg > 1 &&
               ((size_t)nseg * HW_IMG * 16 > ws_size || (N % nseg) != 0))
            nseg >>= 1;

        dim3 grid(HW_IMG / 256, nseg);
        render_fb<<<grid, 256, 0, stream>>>(pos, col, opac, scl, qv, tv, part, N / nseg);

        finalize_kernel<<<HW_IMG / 256, 256, 0, stream>>>(
            part, (float*)d_out, chunk_gauss_p, tile_hw_p, N, nseg);
    }
}